// Round 15
// baseline (361.209 us; speedup 1.0000x reference)
//
#include <hip/hip_runtime.h>

#define BB 16
#define CC 256
#define HW 4096
#define TD3 768
#define TD2 512
#define WQ_N (TD3 * CC)   // 196608
#define WP_N (CC * TD2)   // 131072

typedef __bf16 bf16x8 __attribute__((ext_vector_type(8)));
typedef float f32x4 __attribute__((ext_vector_type(4)));
typedef const __attribute__((address_space(1))) unsigned int glb_u32;
typedef __attribute__((address_space(3))) unsigned int lds_u32;

__device__ inline ushort f2bf(float f) {
    union { float f; uint u; } v; v.f = f;
    uint u = v.u;
    return (ushort)((u + 0x7FFFu + ((u >> 16) & 1u)) >> 16);
}
__device__ inline float bf2f(ushort h) {
    union { uint u; float f; } v; v.u = ((uint)h) << 16;
    return v.f;
}
__device__ inline float bf2f_lo(uint u) {
    union { uint u; float f; } v; v.u = u << 16;
    return v.f;
}
__device__ inline float bf2f_hi(uint u) {
    union { uint u; float f; } v; v.u = u & 0xffff0000u;
    return v.f;
}
__device__ inline uint pack2(float a, float b) {
    return (uint)f2bf(a) | ((uint)f2bf(b) << 16);
}
// lane i <- lane i+1 within each 16-lane DPP row (shuffle-down by 1); lane 15 -> 0
__device__ inline float dpp_shl1(float x) {
    union { float f; int i; } a, r;
    a.f = x;
    r.i = __builtin_amdgcn_update_dpp(0, a.i, 0x101, 0xf, 0xf, true);
    return r.f;
}

// ---------------- K_prep: split w_qkv into bf16 hi + lo; w_proj hi only ----------------
__launch_bounds__(256)
__global__ void k_prep(const float* __restrict__ w_qkv, const float* __restrict__ w_proj,
                       ushort* __restrict__ wq_hi, ushort* __restrict__ wq_lo,
                       ushort* __restrict__ wp_hi) {
    int i = blockIdx.x * 256 + threadIdx.x;
    if (i < WQ_N) {
        float f = w_qkv[i];
        ushort h = f2bf(f);
        wq_hi[i] = h;
        wq_lo[i] = f2bf(f - bf2f(h));
    }
    if (i < WP_N) {
        wp_hi[i] = f2bf(w_proj[i]);
    }
}

// ---------------- K0: x (B,C,HW) f32 -> x_cl (B,HW,C) bf16 ----------------
__launch_bounds__(256)
__global__ void k0_transpose(const float* __restrict__ x, ushort* __restrict__ x_cl) {
    __shared__ float tile[64][65];
    int b = blockIdx.z;
    int n0 = blockIdx.x * 64;
    int c0 = blockIdx.y * 64;
    int t = threadIdx.x;
    const float* xp = x + ((size_t)b * CC + c0) * HW + n0;
    int nl = t & 63;
    int cl0 = t >> 6;
#pragma unroll
    for (int i = 0; i < 16; i++) {
        int cl = cl0 + i * 4;
        tile[cl][nl] = xp[(size_t)cl * HW + nl];
    }
    __syncthreads();
#pragma unroll
    for (int it = 0; it < 2; it++) {
        int item = t + it * 256;
        int n = item >> 3;
        int cc = item & 7;
        uint4 o;
        o.x = pack2(tile[cc * 8 + 0][n], tile[cc * 8 + 1][n]);
        o.y = pack2(tile[cc * 8 + 2][n], tile[cc * 8 + 3][n]);
        o.z = pack2(tile[cc * 8 + 4][n], tile[cc * 8 + 5][n]);
        o.w = pack2(tile[cc * 8 + 6][n], tile[cc * 8 + 7][n]);
        *(uint4*)(x_cl + ((size_t)b * HW + n0 + n) * CC + c0 + cc * 8) = o;
    }
}

// ---------------- K1: split-B GEMM -> qkv planes, all bf16 ----------------
__launch_bounds__(256)
__global__ void k1_qkv(const ushort* __restrict__ x_cl, const ushort* __restrict__ wq_hi,
                       const ushort* __restrict__ wq_lo, ushort* __restrict__ qkv_pl) {
    __shared__ ushort Ald[128][32];
    __shared__ ushort Bh[128][32];
    __shared__ ushort Bl[128][32];
    int b = blockIdx.z;
    int n0 = blockIdx.x * 128;
    int o0 = blockIdx.y * 128;
    int t = threadIdx.x;
    int w = t >> 6, l = t & 63;
    int wn = (w >> 1) * 64, wo = (w & 1) * 64;
    f32x4 acc[4][4];
#pragma unroll
    for (int m = 0; m < 4; m++)
#pragma unroll
        for (int o = 0; o < 4; o++)
#pragma unroll
            for (int r = 0; r < 4; r++) acc[m][o][r] = 0.f;

    const ushort* Ap  = x_cl + ((size_t)b * HW + n0) * CC;
    const ushort* Bph = wq_hi + (size_t)o0 * CC;
    const ushort* Bpl = wq_lo + (size_t)o0 * CC;
    int rowl = (l >> 2);
    int coll = (l & 3) * 8;

    for (int k0 = 0; k0 < CC; k0 += 32) {
#pragma unroll
        for (int i = 0; i < 2; i++) {
            int rbase = w * 32 + i * 16;
            int row = rbase + rowl;
            __builtin_amdgcn_global_load_lds((glb_u32*)(Ap + (size_t)row * CC + k0 + coll),
                                             (lds_u32*)&Ald[rbase][0], 16, 0, 0);
            __builtin_amdgcn_global_load_lds((glb_u32*)(Bph + (size_t)row * CC + k0 + coll),
                                             (lds_u32*)&Bh[rbase][0], 16, 0, 0);
            __builtin_amdgcn_global_load_lds((glb_u32*)(Bpl + (size_t)row * CC + k0 + coll),
                                             (lds_u32*)&Bl[rbase][0], 16, 0, 0);
        }
        __syncthreads();
        bf16x8 af[4], bh[4], bl[4];
#pragma unroll
        for (int m = 0; m < 4; m++) af[m] = *(const bf16x8*)&Ald[wn + m * 16 + (l & 15)][(l >> 4) * 8];
#pragma unroll
        for (int o = 0; o < 4; o++) {
            bh[o] = *(const bf16x8*)&Bh[wo + o * 16 + (l & 15)][(l >> 4) * 8];
            bl[o] = *(const bf16x8*)&Bl[wo + o * 16 + (l & 15)][(l >> 4) * 8];
        }
#pragma unroll
        for (int m = 0; m < 4; m++)
#pragma unroll
            for (int o = 0; o < 4; o++) {
                acc[m][o] = __builtin_amdgcn_mfma_f32_16x16x32_bf16(af[m], bh[o], acc[m][o], 0, 0, 0);
                acc[m][o] = __builtin_amdgcn_mfma_f32_16x16x32_bf16(af[m], bl[o], acc[m][o], 0, 0, 0);
            }
        __syncthreads();
    }
#pragma unroll
    for (int m = 0; m < 4; m++) {
        int nb = n0 + wn + m * 16 + (l >> 4) * 4;
#pragma unroll
        for (int oi = 0; oi < 4; oi++) {
            int o = o0 + wo + oi * 16 + (l & 15);
            uint2 pv;
            pv.x = pack2(acc[m][oi][0], acc[m][oi][1]);
            pv.y = pack2(acc[m][oi][2], acc[m][oi][3]);
            *(uint2*)(qkv_pl + ((size_t)b * 1536 + o) * HW + nb) = pv;
        }
    }
}

// ---------------- K2 v10: v9 + DPP window sharing (halve ds_read_b128 count) ----------------
// LDS 2ch x 36rows x 76 f32; data elems 2..65; pads {0,1,66,67} zeroed once.
// Per (ch,j): ONE b128 read (unit s); win[4..7] via 4x DPP row_shl:1 from lane s+1;
// seg==15 lanes patch from unit 16 (exec-masked read, 4 lanes/wave).
__launch_bounds__(256)
__global__ void k2_dwpw(ushort* __restrict__ qkv_pl, const float* __restrict__ w_dw,
                        const float* __restrict__ w_pw) {
    __shared__ __align__(16) float lds[2][36][76];
    int g = blockIdx.x;
    int strip = blockIdx.y;   // 0..1, 32 output rows each
    int b = blockIdx.z;
    int t = threadIdx.x;
    int y0 = strip * 32;
    const float* wg  = w_dw + (size_t)g * 200;
    const float* wpg = w_pw + (size_t)g * 64;
    const ushort* src = qkv_pl + ((size_t)b * 1536 + g * 8) * HW;
    ushort* dst = qkv_pl + ((size_t)b * 1536 + 768 + g * 8) * HW;

    int rp = t >> 4;      // 0..15 row-pair
    int seg = t & 15;     // 0..15 col quad

    float ag[8][8];       // [o][r*4+k]
#pragma unroll
    for (int o = 0; o < 8; o++)
#pragma unroll
        for (int j = 0; j < 8; j++) ag[o][j] = 0.f;

#pragma unroll 1
    for (int cp = 0; cp < 4; cp++) {
        if (cp) __syncthreads();   // previous pass fully consumed before restaging
        if (cp == 0) {
            if (t < 144) {
                int ch = t / 72, rem = t - ch * 72;
                int row = rem >> 1, side = rem & 1;
                float2 z2 = {0.f, 0.f};
                *(float2*)(&lds[ch][row][side ? 66 : 0]) = z2;
            }
        }
        // stage channels 2cp, 2cp+1: 2ch * 36 rows * 8 units (8 bf16 = 16B) = 576 slots
#pragma unroll
        for (int i = 0; i < 3; i++) {
            int slot = t + i * 256;
            if (slot < 576) {
                int ch = slot / 288;
                int rem = slot - ch * 288;
                int row = rem >> 3;
                int u = rem & 7;
                int yy = y0 - 2 + row;
                uint4 v = {0u, 0u, 0u, 0u};
                if (yy >= 0 && yy < 64)
                    v = *(const uint4*)(src + (size_t)(2 * cp + ch) * HW + yy * 64 + u * 8);
                float f0 = bf2f_lo(v.x), f1 = bf2f_hi(v.x);
                float f2 = bf2f_lo(v.y), f3 = bf2f_hi(v.y);
                float f4 = bf2f_lo(v.z), f5 = bf2f_hi(v.z);
                float f6 = bf2f_lo(v.w), f7 = bf2f_hi(v.w);
                float* p = &lds[ch][row][2 + 8 * u];
                float2 a0 = {f0, f1}, a1 = {f2, f3}, a2 = {f4, f5}, a3 = {f6, f7};
                *(float2*)(p + 0) = a0;
                *(float2*)(p + 2) = a1;
                *(float2*)(p + 4) = a2;
                *(float2*)(p + 6) = a3;
            }
        }
        __syncthreads();
#pragma unroll
        for (int ch = 0; ch < 2; ch++) {
            int c = cp * 2 + ch;
            float dw0[4] = {0.f, 0.f, 0.f, 0.f};
            float dw1[4] = {0.f, 0.f, 0.f, 0.f};
#pragma unroll
            for (int j = 0; j < 6; j++) {
                float4 a = *(const float4*)&lds[ch][rp * 2 + j][4 * seg];
                float4 bsh;
                bsh.x = dpp_shl1(a.x); bsh.y = dpp_shl1(a.y);
                bsh.z = dpp_shl1(a.z); bsh.w = dpp_shl1(a.w);
                if (seg == 15) bsh = *(const float4*)&lds[ch][rp * 2 + j][64];
                float win[8];
                win[0] = a.x;   win[1] = a.y;   win[2] = a.z;   win[3] = a.w;
                win[4] = bsh.x; win[5] = bsh.y; win[6] = bsh.z; win[7] = bsh.w;
                if (j <= 4) {
#pragma unroll
                    for (int dx = 0; dx < 5; dx++) {
                        float wv = wg[c * 25 + j * 5 + dx];
#pragma unroll
                        for (int k = 0; k < 4; k++) dw0[k] += win[dx + k] * wv;
                    }
                }
                if (j >= 1) {
#pragma unroll
                    for (int dx = 0; dx < 5; dx++) {
                        float wv = wg[c * 25 + (j - 1) * 5 + dx];
#pragma unroll
                        for (int k = 0; k < 4; k++) dw1[k] += win[dx + k] * wv;
                    }
                }
            }
#pragma unroll
            for (int o = 0; o < 8; o++) {
                float wv = wpg[o * 8 + c];
#pragma unroll
                for (int k = 0; k < 4; k++) {
                    ag[o][k] += dw0[k] * wv;
                    ag[o][4 + k] += dw1[k] * wv;
                }
            }
        }
    }
    int n0 = (y0 + rp * 2) * 64 + seg * 4;
#pragma unroll
    for (int o = 0; o < 8; o++) {
        uint2 r0, r1;
        r0.x = pack2(ag[o][0], ag[o][1]); r0.y = pack2(ag[o][2], ag[o][3]);
        r1.x = pack2(ag[o][4], ag[o][5]); r1.y = pack2(ag[o][6], ag[o][7]);
        *(uint2*)(dst + (size_t)o * HW + n0) = r0;
        *(uint2*)(dst + (size_t)o * HW + n0 + 64) = r1;
    }
}

// ---------------- K3a: partial vk per (head, batch, half); k,v bf16 ----------------
__launch_bounds__(256)
__global__ void k3_vk(const ushort* __restrict__ qkv_pl, float* __restrict__ vk_buf) {
    __shared__ float vk_partial[4][72];
    int h = blockIdx.x;
    int b = blockIdx.y;
    int s = blockIdx.z;   // 0..1
    size_t base = (size_t)b * 1536 + (h < 32 ? 0 : 768) + (size_t)(h & 31) * 24;
    const ushort* kp = qkv_pl + (base + 8) * HW;
    const ushort* vp = qkv_pl + (base + 16) * HW;
    int t = threadIdx.x;
    float vk[9][8];
#pragma unroll
    for (int e = 0; e < 9; e++)
#pragma unroll
        for (int d = 0; d < 8; d++) vk[e][d] = 0.f;

#pragma unroll
    for (int it = 0; it < 2; it++) {
        int n4 = s * 2048 + (t + it * 256) * 4;
        float4 kf[8], vf[8];
#pragma unroll
        for (int d = 0; d < 8; d++) {
            ushort4 ku = *(const ushort4*)(kp + (size_t)d * HW + n4);
            kf[d].x = fmaxf(bf2f(ku.x), 0.f); kf[d].y = fmaxf(bf2f(ku.y), 0.f);
            kf[d].z = fmaxf(bf2f(ku.z), 0.f); kf[d].w = fmaxf(bf2f(ku.w), 0.f);
        }
#pragma unroll
        for (int e = 0; e < 8; e++) {
            ushort4 vu = *(const ushort4*)(vp + (size_t)e * HW + n4);
            vf[e].x = bf2f(vu.x); vf[e].y = bf2f(vu.y);
            vf[e].z = bf2f(vu.z); vf[e].w = bf2f(vu.w);
        }
#pragma unroll
        for (int e = 0; e < 8; e++)
#pragma unroll
            for (int d = 0; d < 8; d++)
                vk[e][d] += vf[e].x * kf[d].x + vf[e].y * kf[d].y + vf[e].z * kf[d].z + vf[e].w * kf[d].w;
#pragma unroll
        for (int d = 0; d < 8; d++) vk[8][d] += kf[d].x + kf[d].y + kf[d].z + kf[d].w;
    }
#pragma unroll
    for (int e = 0; e < 9; e++)
#pragma unroll
        for (int d = 0; d < 8; d++) {
            float v = vk[e][d];
            for (int off = 32; off > 0; off >>= 1) v += __shfl_xor(v, off);
            vk[e][d] = v;
        }
    int w = t >> 6, l = t & 63;
    if (l == 0) {
#pragma unroll
        for (int e = 0; e < 9; e++)
#pragma unroll
            for (int d = 0; d < 8; d++) vk_partial[w][e * 8 + d] = vk[e][d];
    }
    __syncthreads();
    if (t < 72) {
        float sum = vk_partial[0][t] + vk_partial[1][t] + vk_partial[2][t] + vk_partial[3][t];
        vk_buf[(((size_t)b * 64 + h) * 2 + s) * 72 + t] = sum;
    }
}

// ---------------- K3b: out = (vk . relu(q)) / (k1 . relu(q) + eps); q bf16 ----------------
__launch_bounds__(256)
__global__ void k3_out(const ushort* __restrict__ qkv_pl, const float* __restrict__ vk_buf,
                       ushort* __restrict__ out_cl) {
    __shared__ float vk_s[72];
    int h = blockIdx.x;
    int b = blockIdx.y;
    int s = blockIdx.z;   // 0..3
    size_t base = (size_t)b * 1536 + (h < 32 ? 0 : 768) + (size_t)(h & 31) * 24;
    const ushort* qp = qkv_pl + base * HW;
    int t = threadIdx.x;
    if (t < 72) {
        const float* vb = vk_buf + ((size_t)b * 64 + h) * 2 * 72 + t;
        vk_s[t] = vb[0] + vb[72];
    }
    __syncthreads();
    float vkf[9][8];
#pragma unroll
    for (int e = 0; e < 9; e++)
#pragma unroll
        for (int d = 0; d < 8; d++) vkf[e][d] = vk_s[e * 8 + d];

    int n4 = s * 1024 + t * 4;
    float qa[4][8];
#pragma unroll
    for (int d = 0; d < 8; d++) {
        ushort4 qu = *(const ushort4*)(qp + (size_t)d * HW + n4);
        qa[0][d] = fmaxf(bf2f(qu.x), 0.f); qa[1][d] = fmaxf(bf2f(qu.y), 0.f);
        qa[2][d] = fmaxf(bf2f(qu.z), 0.f); qa[3][d] = fmaxf(bf2f(qu.w), 0.f);
    }
    ushort* dst = out_cl + (size_t)b * HW * TD2 + h * 8;
#pragma unroll
    for (int j = 0; j < 4; j++) {
        float o[9];
#pragma unroll
        for (int e = 0; e < 9; e++) {
            float sum = 0.f;
#pragma unroll
            for (int d = 0; d < 8; d++) sum += vkf[e][d] * qa[j][d];
            o[e] = sum;
        }
        float inv = 1.f / (o[8] + 1e-15f);
        uint4 ov;
        ov.x = pack2(o[0] * inv, o[1] * inv); ov.y = pack2(o[2] * inv, o[3] * inv);
        ov.z = pack2(o[4] * inv, o[5] * inv); ov.w = pack2(o[6] * inv, o[7] * inv);
        *(uint4*)(dst + (size_t)(n4 + j) * TD2) = ov;
    }
}

// ---------------- K4: proj GEMM (hi-only A) + BN + residual, global_load_lds staging ----------------
__launch_bounds__(256)
__global__ void k4_proj(const ushort* __restrict__ out_cl, const ushort* __restrict__ wp_hi,
                        const float* __restrict__ x, const float* __restrict__ gamma,
                        const float* __restrict__ beta, const float* __restrict__ mean,
                        const float* __restrict__ var_, float* __restrict__ out) {
    __shared__ ushort Ah[128][32];
    __shared__ ushort Bld[128][32];
    int b = blockIdx.z;
    int n0 = blockIdx.x * 128;
    int c0 = blockIdx.y * 128;
    int t = threadIdx.x;
    int w = t >> 6, l = t & 63;
    int wc = (w >> 1) * 64, wn = (w & 1) * 64;
    f32x4 acc[4][4];
#pragma unroll
    for (int m = 0; m < 4; m++)
#pragma unroll
        for (int o = 0; o < 4; o++)
#pragma unroll
            for (int r = 0; r < 4; r++) acc[m][o][r] = 0.f;

    const ushort* Aph = wp_hi + (size_t)c0 * TD2;
    const ushort* Bp  = out_cl + ((size_t)b * HW + n0) * TD2;
    int rowl = (l >> 2);
    int coll = (l & 3) * 8;

    for (int k0 = 0; k0 < TD2; k0 += 32) {
#pragma unroll
        for (int i = 0; i < 2; i++) {
            int rbase = w * 32 + i * 16;
            int row = rbase + rowl;
            __builtin_amdgcn_global_load_lds((glb_u32*)(Aph + (size_t)row * TD2 + k0 + coll),
                                             (lds_u32*)&Ah[rbase][0], 16, 0, 0);
            __builtin_amdgcn_global_load_lds((glb_u32*)(Bp + (size_t)row * TD2 + k0 + coll),
                                             (lds_u32*)&Bld[rbase][0], 16, 0, 0);
        }
        __syncthreads();
        bf16x8 ah[4], bf[4];
#pragma unroll
        for (int m = 0; m < 4; m++)
            ah[m] = *(const bf16x8*)&Ah[wc + m * 16 + (l & 15)][(l >> 4) * 8];
#pragma unroll
        for (int ni = 0; ni < 4; ni++) bf[ni] = *(const bf16x8*)&Bld[wn + ni * 16 + (l & 15)][(l >> 4) * 8];
#pragma unroll
        for (int m = 0; m < 4; m++)
#pragma unroll
            for (int ni = 0; ni < 4; ni++)
                acc[m][ni] = __builtin_amdgcn_mfma_f32_16x16x32_bf16(ah[m], bf[ni], acc[m][ni], 0, 0, 0);
        __syncthreads();
    }
#pragma unroll
    for (int m = 0; m < 4; m++) {
        int cb = c0 + wc + m * 16 + (l >> 4) * 4;
        float sc[4], mn[4], bt[4];
#pragma unroll
        for (int r = 0; r < 4; r++) {
            sc[r] = gamma[cb + r] * rsqrtf(var_[cb + r] + 1e-5f);
            mn[r] = mean[cb + r];
            bt[r] = beta[cb + r];
        }
#pragma unroll
        for (int ni = 0; ni < 4; ni++) {
            int n = n0 + wn + ni * 16 + (l & 15);
#pragma unroll
            for (int r = 0; r < 4; r++) {
                size_t idx = ((size_t)b * CC + cb + r) * HW + n;
                out[idx] = x[idx] + (acc[m][ni][r] - mn[r]) * sc[r] + bt[r];
            }
        }
    }
}

extern "C" void kernel_launch(void* const* d_in, const int* in_sizes, int n_in,
                              void* d_out, int out_size, void* d_ws, size_t ws_size,
                              hipStream_t stream) {
    const float* x      = (const float*)d_in[0];
    const float* w_qkv  = (const float*)d_in[1];
    const float* w_dw   = (const float*)d_in[2];
    const float* w_pw   = (const float*)d_in[3];
    const float* w_proj = (const float*)d_in[4];
    const float* gamma  = (const float*)d_in[5];
    const float* beta   = (const float*)d_in[6];
    const float* mean   = (const float*)d_in[7];
    const float* var_   = (const float*)d_in[8];
    float* out = (float*)d_out;

    const size_t static_bytes = ((size_t)2 * WQ_N + WP_N) * 2; // wq hi+lo, wp hi
    const size_t per_batch = (size_t)HW * CC * 2 + (size_t)1536 * HW * 2
                           + (size_t)HW * TD2 * 2 + (size_t)64 * 2 * 72 * 4;
    size_t avail = ws_size > static_bytes ? ws_size - static_bytes : 0;
    int cb = 16;
    while (cb > 1 && (size_t)cb * per_batch > avail) cb >>= 1;

    char* ws = (char*)d_ws;
    ushort* x_cl   = (ushort*)ws;
    ushort* qkv_pl = (ushort*)(ws + (size_t)cb * HW * CC * 2);
    ushort* out_cl = (ushort*)(ws + (size_t)cb * HW * CC * 2 + (size_t)cb * 1536 * HW * 2);
    float*  vk_buf = (float*)(ws + (size_t)cb * HW * CC * 2 + (size_t)cb * 1536 * HW * 2
                                 + (size_t)cb * HW * TD2 * 2);
    char* wsw = ws + (size_t)cb * per_batch;
    ushort* wq_hi = (ushort*)wsw;
    ushort* wq_lo = wq_hi + WQ_N;
    ushort* wp_hi = wq_lo + WQ_N;

    k_prep<<<dim3((WQ_N + 255) / 256), 256, 0, stream>>>(w_qkv, w_proj, wq_hi, wq_lo, wp_hi);

    for (int b0 = 0; b0 < BB; b0 += cb) {
        const float* xc = x + (size_t)b0 * CC * HW;
        float* oc = out + (size_t)b0 * CC * HW;
        k0_transpose<<<dim3(64, 4, cb), 256, 0, stream>>>(xc, x_cl);
        k1_qkv<<<dim3(32, 6, cb), 256, 0, stream>>>(x_cl, wq_hi, wq_lo, qkv_pl);
        k2_dwpw<<<dim3(96, 2, cb), 256, 0, stream>>>(qkv_pl, w_dw, w_pw);
        k3_vk<<<dim3(64, cb, 2), 256, 0, stream>>>(qkv_pl, vk_buf);
        k3_out<<<dim3(64, cb, 4), 256, 0, stream>>>(qkv_pl, vk_buf, out_cl);
        k4_proj<<<dim3(32, 2, cb), 256, 0, stream>>>(out_cl, wp_hi, xc, gamma, beta, mean, var_, oc);
    }
}

// Round 16
// 341.411 us; speedup vs baseline: 1.0580x; 1.0580x over previous
//
#include <hip/hip_runtime.h>

#define BB 16
#define CC 256
#define HW 4096
#define TD3 768
#define TD2 512
#define WQ_N (TD3 * CC)   // 196608
#define WP_N (CC * TD2)   // 131072

typedef __bf16 bf16x8 __attribute__((ext_vector_type(8)));
typedef float f32x4 __attribute__((ext_vector_type(4)));
typedef const __attribute__((address_space(1))) unsigned int glb_u32;
typedef __attribute__((address_space(3))) unsigned int lds_u32;

__device__ inline ushort f2bf(float f) {
    union { float f; uint u; } v; v.f = f;
    uint u = v.u;
    return (ushort)((u + 0x7FFFu + ((u >> 16) & 1u)) >> 16);
}
__device__ inline float bf2f(ushort h) {
    union { uint u; float f; } v; v.u = ((uint)h) << 16;
    return v.f;
}
__device__ inline float bf2f_lo(uint u) {
    union { uint u; float f; } v; v.u = u << 16;
    return v.f;
}
__device__ inline float bf2f_hi(uint u) {
    union { uint u; float f; } v; v.u = u & 0xffff0000u;
    return v.f;
}
__device__ inline uint pack2(float a, float b) {
    return (uint)f2bf(a) | ((uint)f2bf(b) << 16);
}

// ---------------- K_prep: split w_qkv into bf16 hi + lo; w_proj hi only ----------------
__launch_bounds__(256)
__global__ void k_prep(const float* __restrict__ w_qkv, const float* __restrict__ w_proj,
                       ushort* __restrict__ wq_hi, ushort* __restrict__ wq_lo,
                       ushort* __restrict__ wp_hi) {
    int i = blockIdx.x * 256 + threadIdx.x;
    if (i < WQ_N) {
        float f = w_qkv[i];
        ushort h = f2bf(f);
        wq_hi[i] = h;
        wq_lo[i] = f2bf(f - bf2f(h));
    }
    if (i < WP_N) {
        wp_hi[i] = f2bf(w_proj[i]);
    }
}

// ---------------- K0: x (B,C,HW) f32 -> x_cl (B,HW,C) bf16 ----------------
__launch_bounds__(256)
__global__ void k0_transpose(const float* __restrict__ x, ushort* __restrict__ x_cl) {
    __shared__ float tile[64][65];
    int b = blockIdx.z;
    int n0 = blockIdx.x * 64;
    int c0 = blockIdx.y * 64;
    int t = threadIdx.x;
    const float* xp = x + ((size_t)b * CC + c0) * HW + n0;
    int nl = t & 63;
    int cl0 = t >> 6;
#pragma unroll
    for (int i = 0; i < 16; i++) {
        int cl = cl0 + i * 4;
        tile[cl][nl] = xp[(size_t)cl * HW + nl];
    }
    __syncthreads();
#pragma unroll
    for (int it = 0; it < 2; it++) {
        int item = t + it * 256;
        int n = item >> 3;
        int cc = item & 7;
        uint4 o;
        o.x = pack2(tile[cc * 8 + 0][n], tile[cc * 8 + 1][n]);
        o.y = pack2(tile[cc * 8 + 2][n], tile[cc * 8 + 3][n]);
        o.z = pack2(tile[cc * 8 + 4][n], tile[cc * 8 + 5][n]);
        o.w = pack2(tile[cc * 8 + 6][n], tile[cc * 8 + 7][n]);
        *(uint4*)(x_cl + ((size_t)b * HW + n0 + n) * CC + c0 + cc * 8) = o;
    }
}

// ---------------- K1: split-B GEMM -> qkv planes, all bf16 ----------------
__launch_bounds__(256)
__global__ void k1_qkv(const ushort* __restrict__ x_cl, const ushort* __restrict__ wq_hi,
                       const ushort* __restrict__ wq_lo, ushort* __restrict__ qkv_pl) {
    __shared__ ushort Ald[128][32];
    __shared__ ushort Bh[128][32];
    __shared__ ushort Bl[128][32];
    int b = blockIdx.z;
    int n0 = blockIdx.x * 128;
    int o0 = blockIdx.y * 128;
    int t = threadIdx.x;
    int w = t >> 6, l = t & 63;
    int wn = (w >> 1) * 64, wo = (w & 1) * 64;
    f32x4 acc[4][4];
#pragma unroll
    for (int m = 0; m < 4; m++)
#pragma unroll
        for (int o = 0; o < 4; o++)
#pragma unroll
            for (int r = 0; r < 4; r++) acc[m][o][r] = 0.f;

    const ushort* Ap  = x_cl + ((size_t)b * HW + n0) * CC;
    const ushort* Bph = wq_hi + (size_t)o0 * CC;
    const ushort* Bpl = wq_lo + (size_t)o0 * CC;
    int rowl = (l >> 2);
    int coll = (l & 3) * 8;

    for (int k0 = 0; k0 < CC; k0 += 32) {
#pragma unroll
        for (int i = 0; i < 2; i++) {
            int rbase = w * 32 + i * 16;
            int row = rbase + rowl;
            __builtin_amdgcn_global_load_lds((glb_u32*)(Ap + (size_t)row * CC + k0 + coll),
                                             (lds_u32*)&Ald[rbase][0], 16, 0, 0);
            __builtin_amdgcn_global_load_lds((glb_u32*)(Bph + (size_t)row * CC + k0 + coll),
                                             (lds_u32*)&Bh[rbase][0], 16, 0, 0);
            __builtin_amdgcn_global_load_lds((glb_u32*)(Bpl + (size_t)row * CC + k0 + coll),
                                             (lds_u32*)&Bl[rbase][0], 16, 0, 0);
        }
        __syncthreads();
        bf16x8 af[4], bh[4], bl[4];
#pragma unroll
        for (int m = 0; m < 4; m++) af[m] = *(const bf16x8*)&Ald[wn + m * 16 + (l & 15)][(l >> 4) * 8];
#pragma unroll
        for (int o = 0; o < 4; o++) {
            bh[o] = *(const bf16x8*)&Bh[wo + o * 16 + (l & 15)][(l >> 4) * 8];
            bl[o] = *(const bf16x8*)&Bl[wo + o * 16 + (l & 15)][(l >> 4) * 8];
        }
#pragma unroll
        for (int m = 0; m < 4; m++)
#pragma unroll
            for (int o = 0; o < 4; o++) {
                acc[m][o] = __builtin_amdgcn_mfma_f32_16x16x32_bf16(af[m], bh[o], acc[m][o], 0, 0, 0);
                acc[m][o] = __builtin_amdgcn_mfma_f32_16x16x32_bf16(af[m], bl[o], acc[m][o], 0, 0, 0);
            }
        __syncthreads();
    }
#pragma unroll
    for (int m = 0; m < 4; m++) {
        int nb = n0 + wn + m * 16 + (l >> 4) * 4;
#pragma unroll
        for (int oi = 0; oi < 4; oi++) {
            int o = o0 + wo + oi * 16 + (l & 15);
            uint2 pv;
            pv.x = pack2(acc[m][oi][0], acc[m][oi][1]);
            pv.y = pack2(acc[m][oi][2], acc[m][oi][3]);
            *(uint2*)(qkv_pl + ((size_t)b * 1536 + o) * HW + nb) = pv;
        }
    }
}

// ---------------- K2 v9 (reverted best): f32 LDS, b128 window reads, bf16 planes ----------------
// LDS 2ch x 36rows x 76 f32; data elems 2..65; pads {0,1,66,67} zeroed once.
// Staging unpacks bf16->f32; hot loop = aligned float4 window reads (2 per (ch,j)).
__launch_bounds__(256)
__global__ void k2_dwpw(ushort* __restrict__ qkv_pl, const float* __restrict__ w_dw,
                        const float* __restrict__ w_pw) {
    __shared__ __align__(16) float lds[2][36][76];
    int g = blockIdx.x;
    int strip = blockIdx.y;   // 0..1, 32 output rows each
    int b = blockIdx.z;
    int t = threadIdx.x;
    int y0 = strip * 32;
    const float* wg  = w_dw + (size_t)g * 200;
    const float* wpg = w_pw + (size_t)g * 64;
    const ushort* src = qkv_pl + ((size_t)b * 1536 + g * 8) * HW;
    ushort* dst = qkv_pl + ((size_t)b * 1536 + 768 + g * 8) * HW;

    int rp = t >> 4;      // 0..15 row-pair
    int seg = t & 15;     // 0..15 col quad

    float ag[8][8];       // [o][r*4+k]
#pragma unroll
    for (int o = 0; o < 8; o++)
#pragma unroll
        for (int j = 0; j < 8; j++) ag[o][j] = 0.f;

#pragma unroll 1
    for (int cp = 0; cp < 4; cp++) {
        if (cp) __syncthreads();   // previous pass fully consumed before restaging
        if (cp == 0) {
            if (t < 144) {
                int ch = t / 72, rem = t - ch * 72;
                int row = rem >> 1, side = rem & 1;
                float2 z2 = {0.f, 0.f};
                *(float2*)(&lds[ch][row][side ? 66 : 0]) = z2;
            }
        }
        // stage channels 2cp, 2cp+1: 2ch * 36 rows * 8 units (8 bf16 = 16B) = 576 slots
#pragma unroll
        for (int i = 0; i < 3; i++) {
            int slot = t + i * 256;
            if (slot < 576) {
                int ch = slot / 288;
                int rem = slot - ch * 288;
                int row = rem >> 3;
                int u = rem & 7;
                int yy = y0 - 2 + row;
                uint4 v = {0u, 0u, 0u, 0u};
                if (yy >= 0 && yy < 64)
                    v = *(const uint4*)(src + (size_t)(2 * cp + ch) * HW + yy * 64 + u * 8);
                float f0 = bf2f_lo(v.x), f1 = bf2f_hi(v.x);
                float f2 = bf2f_lo(v.y), f3 = bf2f_hi(v.y);
                float f4 = bf2f_lo(v.z), f5 = bf2f_hi(v.z);
                float f6 = bf2f_lo(v.w), f7 = bf2f_hi(v.w);
                float* p = &lds[ch][row][2 + 8 * u];
                float2 a0 = {f0, f1}, a1 = {f2, f3}, a2 = {f4, f5}, a3 = {f6, f7};
                *(float2*)(p + 0) = a0;
                *(float2*)(p + 2) = a1;
                *(float2*)(p + 4) = a2;
                *(float2*)(p + 6) = a3;
            }
        }
        __syncthreads();
#pragma unroll
        for (int ch = 0; ch < 2; ch++) {
            int c = cp * 2 + ch;
            float dw0[4] = {0.f, 0.f, 0.f, 0.f};
            float dw1[4] = {0.f, 0.f, 0.f, 0.f};
#pragma unroll
            for (int j = 0; j < 6; j++) {
                float win[8];
                *(float4*)&win[0] = *(const float4*)&lds[ch][rp * 2 + j][4 * seg];
                *(float4*)&win[4] = *(const float4*)&lds[ch][rp * 2 + j][4 * seg + 4];
                if (j <= 4) {
#pragma unroll
                    for (int dx = 0; dx < 5; dx++) {
                        float wv = wg[c * 25 + j * 5 + dx];
#pragma unroll
                        for (int k = 0; k < 4; k++) dw0[k] += win[dx + k] * wv;
                    }
                }
                if (j >= 1) {
#pragma unroll
                    for (int dx = 0; dx < 5; dx++) {
                        float wv = wg[c * 25 + (j - 1) * 5 + dx];
#pragma unroll
                        for (int k = 0; k < 4; k++) dw1[k] += win[dx + k] * wv;
                    }
                }
            }
#pragma unroll
            for (int o = 0; o < 8; o++) {
                float wv = wpg[o * 8 + c];
#pragma unroll
                for (int k = 0; k < 4; k++) {
                    ag[o][k] += dw0[k] * wv;
                    ag[o][4 + k] += dw1[k] * wv;
                }
            }
        }
    }
    int n0 = (y0 + rp * 2) * 64 + seg * 4;
#pragma unroll
    for (int o = 0; o < 8; o++) {
        uint2 r0, r1;
        r0.x = pack2(ag[o][0], ag[o][1]); r0.y = pack2(ag[o][2], ag[o][3]);
        r1.x = pack2(ag[o][4], ag[o][5]); r1.y = pack2(ag[o][6], ag[o][7]);
        *(uint2*)(dst + (size_t)o * HW + n0) = r0;
        *(uint2*)(dst + (size_t)o * HW + n0 + 64) = r1;
    }
}

// ---------------- K3a: partial vk per (head, batch, half); k,v bf16 ----------------
__launch_bounds__(256)
__global__ void k3_vk(const ushort* __restrict__ qkv_pl, float* __restrict__ vk_buf) {
    __shared__ float vk_partial[4][72];
    int h = blockIdx.x;
    int b = blockIdx.y;
    int s = blockIdx.z;   // 0..1
    size_t base = (size_t)b * 1536 + (h < 32 ? 0 : 768) + (size_t)(h & 31) * 24;
    const ushort* kp = qkv_pl + (base + 8) * HW;
    const ushort* vp = qkv_pl + (base + 16) * HW;
    int t = threadIdx.x;
    float vk[9][8];
#pragma unroll
    for (int e = 0; e < 9; e++)
#pragma unroll
        for (int d = 0; d < 8; d++) vk[e][d] = 0.f;

#pragma unroll
    for (int it = 0; it < 2; it++) {
        int n4 = s * 2048 + (t + it * 256) * 4;
        float4 kf[8], vf[8];
#pragma unroll
        for (int d = 0; d < 8; d++) {
            ushort4 ku = *(const ushort4*)(kp + (size_t)d * HW + n4);
            kf[d].x = fmaxf(bf2f(ku.x), 0.f); kf[d].y = fmaxf(bf2f(ku.y), 0.f);
            kf[d].z = fmaxf(bf2f(ku.z), 0.f); kf[d].w = fmaxf(bf2f(ku.w), 0.f);
        }
#pragma unroll
        for (int e = 0; e < 8; e++) {
            ushort4 vu = *(const ushort4*)(vp + (size_t)e * HW + n4);
            vf[e].x = bf2f(vu.x); vf[e].y = bf2f(vu.y);
            vf[e].z = bf2f(vu.z); vf[e].w = bf2f(vu.w);
        }
#pragma unroll
        for (int e = 0; e < 8; e++)
#pragma unroll
            for (int d = 0; d < 8; d++)
                vk[e][d] += vf[e].x * kf[d].x + vf[e].y * kf[d].y + vf[e].z * kf[d].z + vf[e].w * kf[d].w;
#pragma unroll
        for (int d = 0; d < 8; d++) vk[8][d] += kf[d].x + kf[d].y + kf[d].z + kf[d].w;
    }
#pragma unroll
    for (int e = 0; e < 9; e++)
#pragma unroll
        for (int d = 0; d < 8; d++) {
            float v = vk[e][d];
            for (int off = 32; off > 0; off >>= 1) v += __shfl_xor(v, off);
            vk[e][d] = v;
        }
    int w = t >> 6, l = t & 63;
    if (l == 0) {
#pragma unroll
        for (int e = 0; e < 9; e++)
#pragma unroll
            for (int d = 0; d < 8; d++) vk_partial[w][e * 8 + d] = vk[e][d];
    }
    __syncthreads();
    if (t < 72) {
        float sum = vk_partial[0][t] + vk_partial[1][t] + vk_partial[2][t] + vk_partial[3][t];
        vk_buf[(((size_t)b * 64 + h) * 2 + s) * 72 + t] = sum;
    }
}

// ---------------- K3b: out = (vk . relu(q)) / (k1 . relu(q) + eps); q bf16; 2 iters/block ----------------
__launch_bounds__(256)
__global__ void k3_out(const ushort* __restrict__ qkv_pl, const float* __restrict__ vk_buf,
                       ushort* __restrict__ out_cl) {
    __shared__ float vk_s[72];
    int h = blockIdx.x;
    int b = blockIdx.y;
    int s = blockIdx.z;   // 0..1, 2048 positions each
    size_t base = (size_t)b * 1536 + (h < 32 ? 0 : 768) + (size_t)(h & 31) * 24;
    const ushort* qp = qkv_pl + base * HW;
    int t = threadIdx.x;
    if (t < 72) {
        const float* vb = vk_buf + ((size_t)b * 64 + h) * 2 * 72 + t;
        vk_s[t] = vb[0] + vb[72];
    }
    __syncthreads();
    float vkf[9][8];
#pragma unroll
    for (int e = 0; e < 9; e++)
#pragma unroll
        for (int d = 0; d < 8; d++) vkf[e][d] = vk_s[e * 8 + d];

    ushort* dst = out_cl + (size_t)b * HW * TD2 + h * 8;
#pragma unroll
    for (int it = 0; it < 2; it++) {
        int n4 = s * 2048 + (t + it * 256) * 4;
        float qa[4][8];
#pragma unroll
        for (int d = 0; d < 8; d++) {
            ushort4 qu = *(const ushort4*)(qp + (size_t)d * HW + n4);
            qa[0][d] = fmaxf(bf2f(qu.x), 0.f); qa[1][d] = fmaxf(bf2f(qu.y), 0.f);
            qa[2][d] = fmaxf(bf2f(qu.z), 0.f); qa[3][d] = fmaxf(bf2f(qu.w), 0.f);
        }
#pragma unroll
        for (int j = 0; j < 4; j++) {
            float o[9];
#pragma unroll
            for (int e = 0; e < 9; e++) {
                float sum = 0.f;
#pragma unroll
                for (int d = 0; d < 8; d++) sum += vkf[e][d] * qa[j][d];
                o[e] = sum;
            }
            float inv = 1.f / (o[8] + 1e-15f);
            uint4 ov;
            ov.x = pack2(o[0] * inv, o[1] * inv); ov.y = pack2(o[2] * inv, o[3] * inv);
            ov.z = pack2(o[4] * inv, o[5] * inv); ov.w = pack2(o[6] * inv, o[7] * inv);
            *(uint4*)(dst + (size_t)(n4 + j) * TD2) = ov;
        }
    }
}

// ---------------- K4: proj GEMM (hi-only A) + BN + residual, global_load_lds staging ----------------
__launch_bounds__(256)
__global__ void k4_proj(const ushort* __restrict__ out_cl, const ushort* __restrict__ wp_hi,
                        const float* __restrict__ x, const float* __restrict__ gamma,
                        const float* __restrict__ beta, const float* __restrict__ mean,
                        const float* __restrict__ var_, float* __restrict__ out) {
    __shared__ ushort Ah[128][32];
    __shared__ ushort Bld[128][32];
    int b = blockIdx.z;
    int n0 = blockIdx.x * 128;
    int c0 = blockIdx.y * 128;
    int t = threadIdx.x;
    int w = t >> 6, l = t & 63;
    int wc = (w >> 1) * 64, wn = (w & 1) * 64;
    f32x4 acc[4][4];
#pragma unroll
    for (int m = 0; m < 4; m++)
#pragma unroll
        for (int o = 0; o < 4; o++)
#pragma unroll
            for (int r = 0; r < 4; r++) acc[m][o][r] = 0.f;

    const ushort* Aph = wp_hi + (size_t)c0 * TD2;
    const ushort* Bp  = out_cl + ((size_t)b * HW + n0) * TD2;
    int rowl = (l >> 2);
    int coll = (l & 3) * 8;

    for (int k0 = 0; k0 < TD2; k0 += 32) {
#pragma unroll
        for (int i = 0; i < 2; i++) {
            int rbase = w * 32 + i * 16;
            int row = rbase + rowl;
            __builtin_amdgcn_global_load_lds((glb_u32*)(Aph + (size_t)row * TD2 + k0 + coll),
                                             (lds_u32*)&Ah[rbase][0], 16, 0, 0);
            __builtin_amdgcn_global_load_lds((glb_u32*)(Bp + (size_t)row * TD2 + k0 + coll),
                                             (lds_u32*)&Bld[rbase][0], 16, 0, 0);
        }
        __syncthreads();
        bf16x8 ah[4], bf[4];
#pragma unroll
        for (int m = 0; m < 4; m++)
            ah[m] = *(const bf16x8*)&Ah[wc + m * 16 + (l & 15)][(l >> 4) * 8];
#pragma unroll
        for (int ni = 0; ni < 4; ni++) bf[ni] = *(const bf16x8*)&Bld[wn + ni * 16 + (l & 15)][(l >> 4) * 8];
#pragma unroll
        for (int m = 0; m < 4; m++)
#pragma unroll
            for (int ni = 0; ni < 4; ni++)
                acc[m][ni] = __builtin_amdgcn_mfma_f32_16x16x32_bf16(ah[m], bf[ni], acc[m][ni], 0, 0, 0);
        __syncthreads();
    }
#pragma unroll
    for (int m = 0; m < 4; m++) {
        int cb = c0 + wc + m * 16 + (l >> 4) * 4;
        float4 g4 = *(const float4*)(gamma + cb);
        float4 b4 = *(const float4*)(beta + cb);
        float4 m4 = *(const float4*)(mean + cb);
        float4 v4 = *(const float4*)(var_ + cb);
        float sc[4], mn[4], bt[4];
        sc[0] = g4.x * rsqrtf(v4.x + 1e-5f); sc[1] = g4.y * rsqrtf(v4.y + 1e-5f);
        sc[2] = g4.z * rsqrtf(v4.z + 1e-5f); sc[3] = g4.w * rsqrtf(v4.w + 1e-5f);
        mn[0] = m4.x; mn[1] = m4.y; mn[2] = m4.z; mn[3] = m4.w;
        bt[0] = b4.x; bt[1] = b4.y; bt[2] = b4.z; bt[3] = b4.w;
#pragma unroll
        for (int ni = 0; ni < 4; ni++) {
            int n = n0 + wn + ni * 16 + (l & 15);
#pragma unroll
            for (int r = 0; r < 4; r++) {
                size_t idx = ((size_t)b * CC + cb + r) * HW + n;
                out[idx] = x[idx] + (acc[m][ni][r] - mn[r]) * sc[r] + bt[r];
            }
        }
    }
}

extern "C" void kernel_launch(void* const* d_in, const int* in_sizes, int n_in,
                              void* d_out, int out_size, void* d_ws, size_t ws_size,
                              hipStream_t stream) {
    const float* x      = (const float*)d_in[0];
    const float* w_qkv  = (const float*)d_in[1];
    const float* w_dw   = (const float*)d_in[2];
    const float* w_pw   = (const float*)d_in[3];
    const float* w_proj = (const float*)d_in[4];
    const float* gamma  = (const float*)d_in[5];
    const float* beta   = (const float*)d_in[6];
    const float* mean   = (const float*)d_in[7];
    const float* var_   = (const float*)d_in[8];
    float* out = (float*)d_out;

    const size_t static_bytes = ((size_t)2 * WQ_N + WP_N) * 2; // wq hi+lo, wp hi
    const size_t per_batch = (size_t)HW * CC * 2 + (size_t)1536 * HW * 2
                           + (size_t)HW * TD2 * 2 + (size_t)64 * 2 * 72 * 4;
    size_t avail = ws_size > static_bytes ? ws_size - static_bytes : 0;
    int cb = 16;
    while (cb > 1 && (size_t)cb * per_batch > avail) cb >>= 1;

    char* ws = (char*)d_ws;
    ushort* x_cl   = (ushort*)ws;
    ushort* qkv_pl = (ushort*)(ws + (size_t)cb * HW * CC * 2);
    ushort* out_cl = (ushort*)(ws + (size_t)cb * HW * CC * 2 + (size_t)cb * 1536 * HW * 2);
    float*  vk_buf = (float*)(ws + (size_t)cb * HW * CC * 2 + (size_t)cb * 1536 * HW * 2
                                 + (size_t)cb * HW * TD2 * 2);
    char* wsw = ws + (size_t)cb * per_batch;
    ushort* wq_hi = (ushort*)wsw;
    ushort* wq_lo = wq_hi + WQ_N;
    ushort* wp_hi = wq_lo + WQ_N;

    k_prep<<<dim3((WQ_N + 255) / 256), 256, 0, stream>>>(w_qkv, w_proj, wq_hi, wq_lo, wp_hi);

    for (int b0 = 0; b0 < BB; b0 += cb) {
        const float* xc = x + (size_t)b0 * CC * HW;
        float* oc = out + (size_t)b0 * CC * HW;
        k0_transpose<<<dim3(64, 4, cb), 256, 0, stream>>>(xc, x_cl);
        k1_qkv<<<dim3(32, 6, cb), 256, 0, stream>>>(x_cl, wq_hi, wq_lo, qkv_pl);
        k2_dwpw<<<dim3(96, 2, cb), 256, 0, stream>>>(qkv_pl, w_dw, w_pw);
        k3_vk<<<dim3(64, cb, 2), 256, 0, stream>>>(qkv_pl, vk_buf);
        k3_out<<<dim3(64, cb, 2), 256, 0, stream>>>(qkv_pl, vk_buf, out_cl);
        k4_proj<<<dim3(32, 2, cb), 256, 0, stream>>>(out_cl, wp_hi, xc, gamma, beta, mean, var_, oc);
    }
}